// Round 1
// baseline (956.552 us; speedup 1.0000x reference)
//
#include <hip/hip_runtime.h>

// out[n, i] (i=0..6), out flat [N_ORG*7], float32.
// msg[e] = sum_d ea[e,d] * Y[src[e],d] + C[src[e]]
//   Y[n,d] = sum_j x_src[n,j] * linW[j,d]   (linW is [64, ed] row-major)
//   C[n]   = sum_j x_src[n,j] * linb[j]
// out[n,i] = segsum(msg) + x_org[n,:] @ root_i + b_i

struct RootArgs { const float* root[7]; const float* b[7]; };

__global__ __launch_bounds__(256) void init_out_kernel(
    const float* __restrict__ x_org, RootArgs ra, float* __restrict__ out, int n_org) {
  __shared__ float s_root[7 * 64];
  __shared__ float s_b[7];
  for (int t = threadIdx.x; t < 7 * 64; t += blockDim.x)
    s_root[t] = ra.root[t >> 6][t & 63];
  if (threadIdx.x < 7) s_b[threadIdx.x] = ra.b[threadIdx.x][0];
  __syncthreads();
  int n = blockIdx.x * blockDim.x + threadIdx.x;
  if (n >= n_org) return;
  const float4* xp = (const float4*)(x_org + (size_t)n * 64);
  float acc[7];
#pragma unroll
  for (int i = 0; i < 7; ++i) acc[i] = s_b[i];
  for (int j4 = 0; j4 < 16; ++j4) {
    float4 xv = xp[j4];
    float xa[4] = {xv.x, xv.y, xv.z, xv.w};
#pragma unroll
    for (int u = 0; u < 4; ++u) {
      int j = j4 * 4 + u;
#pragma unroll
      for (int i = 0; i < 7; ++i) acc[i] += xa[u] * s_root[i * 64 + j];
    }
  }
#pragma unroll
  for (int i = 0; i < 7; ++i) out[(size_t)n * 7 + i] = acc[i];
}

// Y precompute, ed==32. 4 nodes per thread; d split in halves of 16 to cap regs.
__global__ __launch_bounds__(256) void compute_y32_kernel(
    const float* __restrict__ x, const float* __restrict__ lw,
    const float* __restrict__ lb, float* __restrict__ Y, float* __restrict__ C, int N) {
  __shared__ float s_lw[64 * 32];
  __shared__ float s_lb[64];
  for (int t = threadIdx.x; t < 64 * 32; t += blockDim.x) s_lw[t] = lw[t];
  for (int t = threadIdx.x; t < 64; t += blockDim.x) s_lb[t] = lb[t];
  __syncthreads();
  int n0 = (blockIdx.x * blockDim.x + threadIdx.x) * 4;
  if (n0 >= N) return;  // N % 4 == 0 for all node types here
  const float4* xp0 = (const float4*)(x + (size_t)(n0 + 0) * 64);
  const float4* xp1 = (const float4*)(x + (size_t)(n0 + 1) * 64);
  const float4* xp2 = (const float4*)(x + (size_t)(n0 + 2) * 64);
  const float4* xp3 = (const float4*)(x + (size_t)(n0 + 3) * 64);
  float accC[4] = {0.f, 0.f, 0.f, 0.f};
#pragma unroll
  for (int half = 0; half < 2; ++half) {
    float a0[16], a1[16], a2[16], a3[16];
#pragma unroll
    for (int d = 0; d < 16; ++d) { a0[d] = 0.f; a1[d] = 0.f; a2[d] = 0.f; a3[d] = 0.f; }
    for (int j4 = 0; j4 < 16; ++j4) {
      float4 v0 = xp0[j4], v1 = xp1[j4], v2 = xp2[j4], v3 = xp3[j4];
      float x0[4] = {v0.x, v0.y, v0.z, v0.w};
      float x1[4] = {v1.x, v1.y, v1.z, v1.w};
      float x2[4] = {v2.x, v2.y, v2.z, v2.w};
      float x3[4] = {v3.x, v3.y, v3.z, v3.w};
#pragma unroll
      for (int u = 0; u < 4; ++u) {
        int j = j4 * 4 + u;
        if (half == 0) {
          float bb = s_lb[j];
          accC[0] += x0[u] * bb; accC[1] += x1[u] * bb;
          accC[2] += x2[u] * bb; accC[3] += x3[u] * bb;
        }
        const float* wrow = &s_lw[j * 32 + half * 16];
#pragma unroll
        for (int d = 0; d < 16; ++d) {
          float w = wrow[d];
          a0[d] += x0[u] * w; a1[d] += x1[u] * w;
          a2[d] += x2[u] * w; a3[d] += x3[u] * w;
        }
      }
    }
#pragma unroll
    for (int q = 0; q < 4; ++q) {
      *(float4*)(Y + (size_t)(n0 + 0) * 32 + half * 16 + q * 4) =
          make_float4(a0[q * 4], a0[q * 4 + 1], a0[q * 4 + 2], a0[q * 4 + 3]);
      *(float4*)(Y + (size_t)(n0 + 1) * 32 + half * 16 + q * 4) =
          make_float4(a1[q * 4], a1[q * 4 + 1], a1[q * 4 + 2], a1[q * 4 + 3]);
      *(float4*)(Y + (size_t)(n0 + 2) * 32 + half * 16 + q * 4) =
          make_float4(a2[q * 4], a2[q * 4 + 1], a2[q * 4 + 2], a2[q * 4 + 3]);
      *(float4*)(Y + (size_t)(n0 + 3) * 32 + half * 16 + q * 4) =
          make_float4(a3[q * 4], a3[q * 4 + 1], a3[q * 4 + 2], a3[q * 4 + 3]);
    }
  }
  C[n0 + 0] = accC[0]; C[n0 + 1] = accC[1];
  C[n0 + 2] = accC[2]; C[n0 + 3] = accC[3];
}

// Y precompute, ed==1.
__global__ __launch_bounds__(256) void compute_y1_kernel(
    const float* __restrict__ x, const float* __restrict__ lw,
    const float* __restrict__ lb, float* __restrict__ Y, float* __restrict__ C, int N) {
  __shared__ float s_lw[64];
  __shared__ float s_lb[64];
  for (int t = threadIdx.x; t < 64; t += blockDim.x) { s_lw[t] = lw[t]; s_lb[t] = lb[t]; }
  __syncthreads();
  int n0 = (blockIdx.x * blockDim.x + threadIdx.x) * 4;
  if (n0 >= N) return;
#pragma unroll
  for (int nn = 0; nn < 4; ++nn) {
    const float4* xp = (const float4*)(x + (size_t)(n0 + nn) * 64);
    float acc = 0.f, accC = 0.f;
    for (int j4 = 0; j4 < 16; ++j4) {
      float4 v = xp[j4];
      float xa[4] = {v.x, v.y, v.z, v.w};
#pragma unroll
      for (int u = 0; u < 4; ++u) {
        int j = j4 * 4 + u;
        acc += xa[u] * s_lw[j];
        accC += xa[u] * s_lb[j];
      }
    }
    Y[n0 + nn] = acc;
    C[n0 + nn] = accC;
  }
}

__global__ __launch_bounds__(256) void edge32_kernel(
    const int* __restrict__ src, const int* __restrict__ dst,
    const float* __restrict__ ea, const float* __restrict__ Y,
    const float* __restrict__ C, float* __restrict__ out, int conv, int nE) {
  int e = blockIdx.x * blockDim.x + threadIdx.x;
  if (e >= nE) return;
  int s = src[e], t = dst[e];
  const float4* eap = (const float4*)(ea + (size_t)e * 32);
  const float4* yp = (const float4*)(Y + (size_t)s * 32);
  float acc = 0.f;
#pragma unroll
  for (int q = 0; q < 8; ++q) {
    float4 a = eap[q], y = yp[q];
    acc += a.x * y.x + a.y * y.y + a.z * y.z + a.w * y.w;
  }
  atomicAdd(out + (size_t)t * 7 + conv, acc + C[s]);
}

__global__ __launch_bounds__(256) void edge1_kernel(
    const int* __restrict__ src, const int* __restrict__ dst,
    const float* __restrict__ ea, const float* __restrict__ Y,
    const float* __restrict__ C, float* __restrict__ out, int conv, int nE) {
  int e = blockIdx.x * blockDim.x + threadIdx.x;
  if (e >= nE) return;
  int s = src[e], t = dst[e];
  float msg = ea[e] * Y[s] + C[s];
  atomicAdd(out + (size_t)t * 7 + conv, msg);
}

// ---- fallback (used only if ws_size too small): direct per-edge compute ----
__global__ __launch_bounds__(256) void edge32_direct_kernel(
    const int* __restrict__ src, const int* __restrict__ dst,
    const float* __restrict__ ea, const float* __restrict__ x,
    const float* __restrict__ lw, const float* __restrict__ lb,
    float* __restrict__ out, int conv, int nE) {
  __shared__ float s_lw[64 * 32];
  __shared__ float s_lb[64];
  for (int t = threadIdx.x; t < 64 * 32; t += blockDim.x) s_lw[t] = lw[t];
  for (int t = threadIdx.x; t < 64; t += blockDim.x) s_lb[t] = lb[t];
  __syncthreads();
  int e = blockIdx.x * blockDim.x + threadIdx.x;
  if (e >= nE) return;
  int s = src[e], t = dst[e];
  float ev[32];
#pragma unroll
  for (int q = 0; q < 8; ++q) {
    float4 a = ((const float4*)(ea + (size_t)e * 32))[q];
    ev[q * 4 + 0] = a.x; ev[q * 4 + 1] = a.y; ev[q * 4 + 2] = a.z; ev[q * 4 + 3] = a.w;
  }
  const float4* xp = (const float4*)(x + (size_t)s * 64);
  float acc = 0.f;
  for (int j4 = 0; j4 < 16; ++j4) {
    float4 xv = xp[j4];
    float xa[4] = {xv.x, xv.y, xv.z, xv.w};
#pragma unroll
    for (int u = 0; u < 4; ++u) {
      int j = j4 * 4 + u;
      float wj = s_lb[j];
#pragma unroll
      for (int d = 0; d < 32; ++d) wj += s_lw[j * 32 + d] * ev[d];
      acc += xa[u] * wj;
    }
  }
  atomicAdd(out + (size_t)t * 7 + conv, acc);
}

__global__ __launch_bounds__(256) void edge1_direct_kernel(
    const int* __restrict__ src, const int* __restrict__ dst,
    const float* __restrict__ ea, const float* __restrict__ x,
    const float* __restrict__ lw, const float* __restrict__ lb,
    float* __restrict__ out, int conv, int nE) {
  __shared__ float s_lw[64];
  __shared__ float s_lb[64];
  for (int t = threadIdx.x; t < 64; t += blockDim.x) { s_lw[t] = lw[t]; s_lb[t] = lb[t]; }
  __syncthreads();
  int e = blockIdx.x * blockDim.x + threadIdx.x;
  if (e >= nE) return;
  int s = src[e], t = dst[e];
  float ev = ea[e];
  const float4* xp = (const float4*)(x + (size_t)s * 64);
  float acc = 0.f;
  for (int j4 = 0; j4 < 16; ++j4) {
    float4 xv = xp[j4];
    float xa[4] = {xv.x, xv.y, xv.z, xv.w};
#pragma unroll
    for (int u = 0; u < 4; ++u) {
      int j = j4 * 4 + u;
      acc += xa[u] * (s_lw[j] * ev + s_lb[j]);
    }
  }
  atomicAdd(out + (size_t)t * 7 + conv, acc);
}

extern "C" void kernel_launch(void* const* d_in, const int* in_sizes, int n_in,
                              void* d_out, int out_size, void* d_ws, size_t ws_size,
                              hipStream_t stream) {
  const float* xs[3] = {(const float*)d_in[0], (const float*)d_in[1], (const float*)d_in[2]};
  int Ns[3] = {in_sizes[0] / 64, in_sizes[1] / 64, in_sizes[2] / 64};
  const int stype[7] = {0, 1, 2, 0, 0, 1, 2};  // ind, org, ext, ind, ind, org, ext
  float* out = (float*)d_out;
  int n_org = Ns[1];

  RootArgs ra;
  for (int i = 0; i < 7; ++i) {
    int base = 3 + i * 7;
    ra.root[i] = (const float*)d_in[base + 5];
    ra.b[i] = (const float*)d_in[base + 6];
  }
  init_out_kernel<<<(n_org + 255) / 256, 256, 0, stream>>>(xs[1], ra, out, n_org);

  size_t maxN = (size_t)Ns[0];
  size_t needY = maxN * 32 * sizeof(float);
  size_t needC = maxN * sizeof(float);
  bool use_ws = ws_size >= needY + needC;
  float* Y = (float*)d_ws;
  float* C = (float*)((char*)d_ws + needY);

  for (int i = 0; i < 7; ++i) {
    int base = 3 + i * 7;
    const int* srcp = (const int*)d_in[base + 0];
    const int* dstp = (const int*)d_in[base + 1];
    const float* ea = (const float*)d_in[base + 2];
    const float* lw = (const float*)d_in[base + 3];
    const float* lb = (const float*)d_in[base + 4];
    const float* x = xs[stype[i]];
    int N = Ns[stype[i]];
    int nE = in_sizes[base];
    int ed = in_sizes[base + 2] / nE;
    int egrid = (nE + 255) / 256;
    int ygrid = (N / 4 + 255) / 256;
    if (use_ws) {
      if (ed == 32) {
        compute_y32_kernel<<<ygrid, 256, 0, stream>>>(x, lw, lb, Y, C, N);
        edge32_kernel<<<egrid, 256, 0, stream>>>(srcp, dstp, ea, Y, C, out, i, nE);
      } else {
        compute_y1_kernel<<<ygrid, 256, 0, stream>>>(x, lw, lb, Y, C, N);
        edge1_kernel<<<egrid, 256, 0, stream>>>(srcp, dstp, ea, Y, C, out, i, nE);
      }
    } else {
      if (ed == 32) {
        edge32_direct_kernel<<<egrid, 256, 0, stream>>>(srcp, dstp, ea, x, lw, lb, out, i, nE);
      } else {
        edge1_direct_kernel<<<egrid, 256, 0, stream>>>(srcp, dstp, ea, x, lw, lb, out, i, nE);
      }
    }
  }
}